// Round 8
// baseline (254.744 us; speedup 1.0000x reference)
//
#include <hip/hip_runtime.h>
#include <stdint.h>

// Problem constants (B=8, T=2048, D=256, K=8192)
#define M_TOK 16384
#define DIM   256
#define KCB   8192
#define NCG   128                  // code-groups of 64 codes (one per wave)
#define NMS   32                   // m-slices of 512 rows (one per wave)
#define SHIFT 512.0f               // positivity shift for score packing
#define INV_N (1.0f / 4194304.0f)  // 1/(B*T*D)
#define SC1   0x7F7F7F7F           // E8M0 scale bytes = 2^0 (op_sel-proof)

typedef __attribute__((ext_vector_type(4))) float f32x4;
typedef __attribute__((ext_vector_type(8))) int   i32x8;

// pack 4 floats -> 4 fp8 e4m3 bytes (one dword)
static __device__ __forceinline__ int pk4(float4 f) {
    int o = __builtin_amdgcn_cvt_pk_fp8_f32(f.x, f.y, 0, false);
    o     = __builtin_amdgcn_cvt_pk_fp8_f32(f.z, f.w, o, true);
    return o;
}

// ---------------------------------------------------------------- kernel 1
// Prep: cbt[chunk][code][16B] = fp8(-c) k-chunk-major; chalf = 0.5||c||^2 +
// SHIFT; xq[chunk][row][16B] = fp8(x). Blocks 0..255: codebook (32 codes
// each); 256..767: xs (32 rows each). Block 0 zeroes the finalize ticket.
__global__ void k_prep(const float* __restrict__ cb,
                       unsigned char* __restrict__ cbt,
                       float* __restrict__ chalf,
                       const float* __restrict__ xs,
                       unsigned char* __restrict__ xq,
                       uint32_t* __restrict__ cnt) {
    const int bid = blockIdx.x;
    if (bid == 0 && threadIdx.x == 0) *cnt = 0;
    const int w    = threadIdx.x >> 6;
    const int l    = threadIdx.x & 63;
    const int idx  = l & 31;           // code or row within block
    const int sub  = l >> 5;
    const int grp8 = w * 2 + sub;      // 0..7, two chunks each

    if (bid < 256) {                   // ---- codebook part
        __shared__ float part[8][32];
        const int c0 = bid * 32;
        const float* row = cb + (size_t)(c0 + idx) * DIM;
        float s = 0.0f;
        #pragma unroll
        for (int j = 0; j < 2; j++) {
            int ch = grp8 * 2 + j;
            const float* p = row + ch * 16;
            float4 a = *(const float4*)(p);
            float4 b = *(const float4*)(p + 4);
            float4 c = *(const float4*)(p + 8);
            float4 d = *(const float4*)(p + 12);
            s += a.x*a.x + a.y*a.y + a.z*a.z + a.w*a.w
               + b.x*b.x + b.y*b.y + b.z*b.z + b.w*b.w
               + c.x*c.x + c.y*c.y + c.z*c.z + c.w*c.w
               + d.x*d.x + d.y*d.y + d.z*d.z + d.w*d.w;
            float4 na = {-a.x, -a.y, -a.z, -a.w};
            float4 nb = {-b.x, -b.y, -b.z, -b.w};
            float4 nc = {-c.x, -c.y, -c.z, -c.w};
            float4 nd = {-d.x, -d.y, -d.z, -d.w};
            uint4 r;
            r.x = (unsigned)pk4(na); r.y = (unsigned)pk4(nb);
            r.z = (unsigned)pk4(nc); r.w = (unsigned)pk4(nd);
            *(uint4*)(cbt + ((size_t)ch * KCB + c0 + idx) * 16) = r;
        }
        part[grp8][idx] = s;
        __syncthreads();
        if (w == 0 && l < 32) {
            float t = 0.0f;
            #pragma unroll
            for (int i = 0; i < 8; i++) t += part[i][l];
            chalf[c0 + l] = 0.5f * t + SHIFT;
        }
    } else {                           // ---- xs part (no norm, no negate)
        const int r0  = (bid - 256) * 32;
        const float* row = xs + (size_t)(r0 + idx) * DIM;
        #pragma unroll
        for (int j = 0; j < 2; j++) {
            int ch = grp8 * 2 + j;
            const float* p = row + ch * 16;
            uint4 r;
            r.x = (unsigned)pk4(*(const float4*)(p));
            r.y = (unsigned)pk4(*(const float4*)(p + 4));
            r.z = (unsigned)pk4(*(const float4*)(p + 8));
            r.w = (unsigned)pk4(*(const float4*)(p + 12));
            *(uint4*)(xq + ((size_t)ch * M_TOK + r0 + idx) * 16) = r;
        }
    }
}

// ---------------------------------------------------------------- kernel 2
// R19 = R18 structure with two fixes:
//  (1) A-prefetch distance was +2 (step S+1's ks0 was NEVER loaded; 31/32
//      steps multiplied the wrong row-block in the ks0 half -> absmax 4.5e-2).
//      Now (S+1)&31: prologue loads step0, each ASTEP prefetches step S+1.
//  (2) key packing reverted to the R1-verified scheme (absmax 0.0 x5 runs):
//      key = (score & 0xFFFFFC00) | id10, id10 = global code & 1023
//      = (cg&15)*64 + ct*16 + col (wave-uniform base + local id).
// Structure: B-resident (64 VGPR), free-running waves, no LDS/barriers/DMA.
// Block = 4 waves, same m-slice, consecutive code-groups -> A-step L1 reuse;
// bid mapping gives each XCD 4 m-slices (xq slice L2-resident).
// Per 16-row step: 4 global_load_dwordx4 + 8 MFMA + ~70 VALU + 4 stores.
// ~118 VGPR target < 128 cap (launch_bounds 256,4); grid 1024 = 4/CU exact.
__global__ __launch_bounds__(256, 4) void k_gemm_argmin(
    const unsigned char* __restrict__ xq,      // [16][M_TOK][16] fp8 of x
    const unsigned char* __restrict__ cbt,     // [16][KCB][16] fp8 of -c
    const float* __restrict__ chalf,           // [KCB] = 0.5||c||^2+SHIFT
    uint32_t* __restrict__ pkey)               // [NCG][M_TOK]
{
    const int tid  = threadIdx.x;
    const int w    = tid >> 6;
    const int l    = tid & 63;
    const int col  = l & 15;
    const int quad = l >> 4;
    const int bid  = blockIdx.x;
    // XCD-aware: bid%8 = XCD (heuristic) -> ms in [4x,4x+4): 4 slices/XCD
    const int ms   = (bid & 7) * 4 + ((bid >> 3) & 3);   // 0..31
    const int cg   = (bid >> 5) * 4 + w;                  // 0..127
    const int row0base = ms * 512;
    const int chA = quad * 2, chB = 8 + quad * 2;
    const uint32_t idbase = (uint32_t)((cg & 15) << 6);   // id10 base

    // ---- resident B panel: codes cg*64 + ct*16 + col, 64 VGPRs
    i32x8 bfr[4][2];
    #pragma unroll
    for (int ct = 0; ct < 4; ct++) {
        const int code = cg * 64 + ct * 16 + col;
        #pragma unroll
        for (int ks = 0; ks < 2; ks++) {
            const int ch = ks * 8 + quad * 2;
            union { uint4 q[2]; i32x8 v; } bb;
            bb.q[0] = *(const uint4*)(cbt + ((size_t)ch * KCB + code) * 16);
            bb.q[1] = *(const uint4*)(cbt + ((size_t)(ch + 1) * KCB + code) * 16);
            bfr[ct][ks] = bb.v;
        }
    }
    float cs[4];
    #pragma unroll
    for (int ct = 0; ct < 4; ct++)
        cs[ct] = chalf[cg * 64 + ct * 16 + col];

// one 16-row step: ks1-A load -> ks0 MFMAs (hide ks1 latency) -> next-step
// ks0-A load -> ks1 MFMAs -> fold+16-lane reduce+store (hides next load).
// Scores bit-identical to R1 (same C-init + ks0->ks1 chain + same key pack).
#define ASTEP(S, C0a, C0b, N0a, N0b)                                          \
    {                                                                         \
        const int row0 = row0base + (S) * 16;                                 \
        const size_t arow = (size_t)(row0 + col) * 16;                        \
        uint4 A1a = *(const uint4*)(xq + (size_t)chB * (M_TOK * 16) + arow);  \
        uint4 A1b = *(const uint4*)(xq + (size_t)(chB + 1) * (M_TOK * 16) + arow); \
        union { uint4 q[2]; i32x8 v; } ua0; ua0.q[0] = C0a; ua0.q[1] = C0b;   \
        f32x4 acc[4];                                                         \
        _Pragma("unroll")                                                     \
        for (int ct = 0; ct < 4; ct++) {                                      \
            f32x4 c4 = {cs[ct], cs[ct], cs[ct], cs[ct]};                      \
            acc[ct] = __builtin_amdgcn_mfma_scale_f32_16x16x128_f8f6f4(       \
                ua0.v, bfr[ct][0], c4, 0, 0, 0, SC1, 0, SC1);                 \
        }                                                                     \
        const size_t nrow = (size_t)(row0base + (((S) + 1) & 31) * 16 + col) * 16; \
        N0a = *(const uint4*)(xq + (size_t)chA * (M_TOK * 16) + nrow);        \
        N0b = *(const uint4*)(xq + (size_t)(chA + 1) * (M_TOK * 16) + nrow);  \
        union { uint4 q[2]; i32x8 v; } ua1; ua1.q[0] = A1a; ua1.q[1] = A1b;   \
        _Pragma("unroll")                                                     \
        for (int ct = 0; ct < 4; ct++)                                        \
            acc[ct] = __builtin_amdgcn_mfma_scale_f32_16x16x128_f8f6f4(       \
                ua1.v, bfr[ct][1], acc[ct], 0, 0, 0, SC1, 0, SC1);            \
        uint32_t best4[4];                                                    \
        _Pragma("unroll")                                                     \
        for (int rg = 0; rg < 4; rg++) {                                      \
            best4[rg] = (__float_as_uint(acc[0][rg]) & 0xFFFFFC00u)           \
                        | (idbase + (uint32_t)col);                           \
            _Pragma("unroll")                                                 \
            for (int ct = 1; ct < 4; ct++) {                                  \
                uint32_t key = (__float_as_uint(acc[ct][rg]) & 0xFFFFFC00u)   \
                               | (idbase + (uint32_t)(ct * 16 + col));        \
                if (key < best4[rg]) best4[rg] = key;                         \
            }                                                                 \
        }                                                                     \
        _Pragma("unroll")                                                     \
        for (int off = 1; off < 16; off <<= 1)                                \
            _Pragma("unroll")                                                 \
            for (int rg = 0; rg < 4; rg++) {                                  \
                uint32_t o = __shfl_xor(best4[rg], off);                      \
                if (o < best4[rg]) best4[rg] = o;                             \
            }                                                                 \
        if (col == 0) {                                                       \
            _Pragma("unroll")                                                 \
            for (int rg = 0; rg < 4; rg++)                                    \
                pkey[(size_t)cg * M_TOK + row0 + quad * 4 + rg] = best4[rg];  \
        }                                                                     \
    }

    uint4 A0a, A0b, N0a, N0b;
    {
        const size_t arow = (size_t)(row0base + col) * 16;
        A0a = *(const uint4*)(xq + (size_t)chA * (M_TOK * 16) + arow);
        A0b = *(const uint4*)(xq + (size_t)(chA + 1) * (M_TOK * 16) + arow);
    }
    #pragma unroll 1
    for (int s = 0; s < 32; s += 2) {
        ASTEP(s,     A0a, A0b, N0a, N0b)
        ASTEP(s + 1, N0a, N0b, A0a, A0b)
    }
#undef ASTEP
}

// ---------------------------------------------------------------- kernel 3
// Per row: min over 128 group keys -> final code; exact fp32 ||x-c||^2;
// per-block LDS reduce -> partial[bid]; fused k_write via release/acquire
// ticket: the 4096th block deterministically sums partial[0..4096) in fixed
// order and writes out.
__global__ void k_finalize(const uint32_t* __restrict__ pkey,
                           const float4* __restrict__ xs4,
                           const float4* __restrict__ cb4,
                           float* __restrict__ partial,
                           uint32_t* __restrict__ cnt,
                           float* __restrict__ out) {
    __shared__ float sblk[4];
    __shared__ int   last;
    const int w   = threadIdx.x >> 6;
    const int l   = threadIdx.x & 63;
    const int row = blockIdx.x * 4 + w;

    uint32_t k1 = pkey[(size_t)l * M_TOK + row];          // cg = l
    uint32_t k2 = pkey[(size_t)(64 + l) * M_TOK + row];   // cg = 64+l
    uint32_t k;  int g;
    if (k2 < k1) { k = k2; g = 64 + l; } else { k = k1; g = l; }
    #pragma unroll
    for (int off = 1; off < 64; off <<= 1) {
        uint32_t ok = __shfl_xor(k, off);
        int      og = __shfl_xor(g, off);
        if (ok < k || (ok == k && og < g)) { k = ok; g = og; }
    }
    // key low 10 bits = global code & 1023; g>>4 = which 1024-code group
    const int code = (g >> 4) * 1024 + (int)(k & 1023u);

    float4 x = xs4[(size_t)row * 64 + l];
    float4 c = cb4[(size_t)code * 64 + l];
    float dx = x.x - c.x, dy = x.y - c.y, dz = x.z - c.z, dw = x.w - c.w;
    float s = dx * dx + dy * dy + dz * dz + dw * dw;
    #pragma unroll
    for (int off = 32; off; off >>= 1) s += __shfl_xor(s, off);
    if (l == 0) sblk[w] = s;
    __syncthreads();
    if (threadIdx.x == 0) {
        partial[blockIdx.x] = sblk[0] + sblk[1] + sblk[2] + sblk[3];
        __threadfence();                         // release partial
        uint32_t old = atomicAdd(cnt, 1u);       // device-scope
        last = (old == 4095u) ? 1 : 0;
    }
    __syncthreads();
    if (last) {
        __threadfence();                         // acquire all partials
        float t = 0.0f;
        for (int i = threadIdx.x; i < 4096; i += 256) t += partial[i];
        #pragma unroll
        for (int off = 32; off; off >>= 1) t += __shfl_xor(t, off);
        __syncthreads();                         // sblk reuse
        if (l == 0) sblk[w] = t;
        __syncthreads();
        if (threadIdx.x == 0) {
            float tt = sblk[0] + sblk[1] + sblk[2] + sblk[3];
            float commit = tt * INV_N;
            out[0] = 0.25f * commit;   // loss
            out[1] = commit;           // commit_loss
        }
    }
}

extern "C" void kernel_launch(void* const* d_in, const int* in_sizes, int n_in,
                              void* d_out, int out_size, void* d_ws, size_t ws_size,
                              hipStream_t stream) {
    const float* xs = (const float*)d_in[0];
    // d_in[1] = ilens (int64, all == T) -> slice is a no-op, unused
    const float* cb = (const float*)d_in[2];

    char* ws = (char*)d_ws;
    uint32_t*      cnt     = (uint32_t*)(ws);                       // 4 B
    float*         partial = (float*)(ws + 256);                    // 16 KiB
    float*         chalf   = (float*)(ws + 16640);                  // 32 KiB
    unsigned char* cbt     = (unsigned char*)(ws + 49408);          // 2 MiB
    unsigned char* xq      = (unsigned char*)(ws + 2146560);        // 4 MiB
    uint32_t*      pkey    = (uint32_t*)(ws + 6340864);             // 8 MiB

    k_prep<<<768, 256, 0, stream>>>(cb, cbt, chalf, xs, xq, cnt);
    k_gemm_argmin<<<1024, 256, 0, stream>>>(xq, cbt, chalf, pkey);
    k_finalize<<<4096, 256, 0, stream>>>(pkey, (const float4*)xs,
                                         (const float4*)cb, partial, cnt,
                                         (float*)d_out);
}

// Round 9
// 218.177 us; speedup vs baseline: 1.1676x; 1.1676x over previous
//
#include <hip/hip_runtime.h>
#include <stdint.h>

// Problem constants (B=8, T=2048, D=256, K=8192)
#define M_TOK 16384
#define DIM   256
#define KCB   8192
#define NCG   128                  // code-groups of 64 codes (one per wave)
#define SHIFT 512.0f               // positivity shift for score packing
#define INV_N (1.0f / 4194304.0f)  // 1/(B*T*D)
#define SC1   0x7F7F7F7F           // E8M0 scale bytes = 2^0 (op_sel-proof)

typedef __attribute__((ext_vector_type(4))) float f32x4;
typedef __attribute__((ext_vector_type(8))) int   i32x8;

// pack 4 floats -> 4 fp8 e4m3 bytes (one dword)
static __device__ __forceinline__ int pk4(float4 f) {
    int o = __builtin_amdgcn_cvt_pk_fp8_f32(f.x, f.y, 0, false);
    o     = __builtin_amdgcn_cvt_pk_fp8_f32(f.z, f.w, o, true);
    return o;
}

// ---------------------------------------------------------------- kernel 1
// Prep: cbt[chunk][code][16B] = fp8(-c) k-chunk-major; chalf = 0.5||c||^2 +
// SHIFT; xq[chunk][row][16B] = fp8(x). Blocks 0..255: codebook (32 codes
// each); 256..767: xs (32 rows each). Block 0 zeroes the finalize ticket.
// (proven absmax 0.0 in R19)
__global__ void k_prep(const float* __restrict__ cb,
                       unsigned char* __restrict__ cbt,
                       float* __restrict__ chalf,
                       const float* __restrict__ xs,
                       unsigned char* __restrict__ xq,
                       uint32_t* __restrict__ cnt) {
    const int bid = blockIdx.x;
    if (bid == 0 && threadIdx.x == 0) *cnt = 0;
    const int w    = threadIdx.x >> 6;
    const int l    = threadIdx.x & 63;
    const int idx  = l & 31;           // code or row within block
    const int sub  = l >> 5;
    const int grp8 = w * 2 + sub;      // 0..7, two chunks each

    if (bid < 256) {                   // ---- codebook part
        __shared__ float part[8][32];
        const int c0 = bid * 32;
        const float* row = cb + (size_t)(c0 + idx) * DIM;
        float s = 0.0f;
        #pragma unroll
        for (int j = 0; j < 2; j++) {
            int ch = grp8 * 2 + j;
            const float* p = row + ch * 16;
            float4 a = *(const float4*)(p);
            float4 b = *(const float4*)(p + 4);
            float4 c = *(const float4*)(p + 8);
            float4 d = *(const float4*)(p + 12);
            s += a.x*a.x + a.y*a.y + a.z*a.z + a.w*a.w
               + b.x*b.x + b.y*b.y + b.z*b.z + b.w*b.w
               + c.x*c.x + c.y*c.y + c.z*c.z + c.w*c.w
               + d.x*d.x + d.y*d.y + d.z*d.z + d.w*d.w;
            float4 na = {-a.x, -a.y, -a.z, -a.w};
            float4 nb = {-b.x, -b.y, -b.z, -b.w};
            float4 nc = {-c.x, -c.y, -c.z, -c.w};
            float4 nd = {-d.x, -d.y, -d.z, -d.w};
            uint4 r;
            r.x = (unsigned)pk4(na); r.y = (unsigned)pk4(nb);
            r.z = (unsigned)pk4(nc); r.w = (unsigned)pk4(nd);
            *(uint4*)(cbt + ((size_t)ch * KCB + c0 + idx) * 16) = r;
        }
        part[grp8][idx] = s;
        __syncthreads();
        if (w == 0 && l < 32) {
            float t = 0.0f;
            #pragma unroll
            for (int i = 0; i < 8; i++) t += part[i][l];
            chalf[c0 + l] = 0.5f * t + SHIFT;
        }
    } else {                           // ---- xs part (no norm, no negate)
        const int r0  = (bid - 256) * 32;
        const float* row = xs + (size_t)(r0 + idx) * DIM;
        #pragma unroll
        for (int j = 0; j < 2; j++) {
            int ch = grp8 * 2 + j;
            const float* p = row + ch * 16;
            uint4 r;
            r.x = (unsigned)pk4(*(const float4*)(p));
            r.y = (unsigned)pk4(*(const float4*)(p + 4));
            r.z = (unsigned)pk4(*(const float4*)(p + 8));
            r.w = (unsigned)pk4(*(const float4*)(p + 12));
            *(uint4*)(xq + ((size_t)ch * M_TOK + r0 + idx) * 16) = r;
        }
    }
}

// ---------------------------------------------------------------- kernel 2
// R20: B-resident free-running GEMM+argmin, spill-fixed. R19 post-mortem:
// __launch_bounds__(256,4) empirically caps VGPRs at 64 (session law: cap
// ~= 512/(2N); R16/R19 both spilled the 64-reg B panel -> scratch reloads
// every step -> 3% util). Fix: (256,2) -> cap 128; body trimmed to ~116 by
// dropping cross-step prefetch rotation (R18's bug source): straight-line
// step {load 4x dwordx4 -> 8 MFMA -> fold -> shfl x4 -> store}. Loads are
// L1/L2-warm (4 waves/block read identical A addresses) and the compiler
// hoists next-step loads freely (no barriers). pkey layout [M][NCG] so
// finalize reads coalesced (R19's [NCG][M] was a 64KB-stride gather).
__global__ __launch_bounds__(256, 2) void k_gemm_argmin(
    const unsigned char* __restrict__ xq,      // [16][M_TOK][16] fp8 of x
    const unsigned char* __restrict__ cbt,     // [16][KCB][16] fp8 of -c
    const float* __restrict__ chalf,           // [KCB] = 0.5||c||^2+SHIFT
    uint32_t* __restrict__ pkey)               // [M_TOK][NCG]
{
    const int tid  = threadIdx.x;
    const int w    = tid >> 6;
    const int l    = tid & 63;
    const int col  = l & 15;
    const int quad = l >> 4;
    const int bid  = blockIdx.x;
    // XCD-aware: bid%8 = XCD (heuristic) -> ms in [4x,4x+4): 4 slices/XCD
    const int ms   = (bid & 7) * 4 + ((bid >> 3) & 3);   // 0..31
    const int cg   = (bid >> 5) * 4 + w;                  // 0..127
    const int row0base = ms * 512;
    const int chA = quad * 2, chB = 8 + quad * 2;
    const uint32_t idbase = (uint32_t)((cg & 15) << 6);   // id10 base

    // ---- resident B panel: codes cg*64 + ct*16 + col, 64 VGPRs
    i32x8 bfr[4][2];
    #pragma unroll
    for (int ct = 0; ct < 4; ct++) {
        const int code = cg * 64 + ct * 16 + col;
        #pragma unroll
        for (int ks = 0; ks < 2; ks++) {
            const int ch = ks * 8 + quad * 2;
            union { uint4 q[2]; i32x8 v; } bb;
            bb.q[0] = *(const uint4*)(cbt + ((size_t)ch * KCB + code) * 16);
            bb.q[1] = *(const uint4*)(cbt + ((size_t)(ch + 1) * KCB + code) * 16);
            bfr[ct][ks] = bb.v;
        }
    }
    float cs[4];
    #pragma unroll
    for (int ct = 0; ct < 4; ct++)
        cs[ct] = chalf[cg * 64 + ct * 16 + col];

    #pragma unroll 1
    for (int s = 0; s < 32; ++s) {
        const int row0 = row0base + s * 16;
        const size_t arow = (size_t)(row0 + col) * 16;
        // all 4 A-loads up front (max memory-level parallelism; 16 VGPRs)
        uint4 A0a = *(const uint4*)(xq + (size_t)chA * (M_TOK * 16) + arow);
        uint4 A0b = *(const uint4*)(xq + (size_t)(chA + 1) * (M_TOK * 16) + arow);
        uint4 A1a = *(const uint4*)(xq + (size_t)chB * (M_TOK * 16) + arow);
        uint4 A1b = *(const uint4*)(xq + (size_t)(chB + 1) * (M_TOK * 16) + arow);
        union { uint4 q[2]; i32x8 v; } ua0; ua0.q[0] = A0a; ua0.q[1] = A0b;
        union { uint4 q[2]; i32x8 v; } ua1; ua1.q[0] = A1a; ua1.q[1] = A1b;

        // scores: C-init with cs splat, ks0 then ks1 (R1-identical chain)
        f32x4 acc[4];
        #pragma unroll
        for (int ct = 0; ct < 4; ct++) {
            f32x4 c4 = {cs[ct], cs[ct], cs[ct], cs[ct]};
            acc[ct] = __builtin_amdgcn_mfma_scale_f32_16x16x128_f8f6f4(
                ua0.v, bfr[ct][0], c4, 0, 0, 0, SC1, 0, SC1);
        }
        #pragma unroll
        for (int ct = 0; ct < 4; ct++)
            acc[ct] = __builtin_amdgcn_mfma_scale_f32_16x16x128_f8f6f4(
                ua1.v, bfr[ct][1], acc[ct], 0, 0, 0, SC1, 0, SC1);

        // fold to packed keys (R1-verified scheme: score&~1023 | id10)
        uint32_t best4[4];
        #pragma unroll
        for (int rg = 0; rg < 4; rg++) {
            best4[rg] = (__float_as_uint(acc[0][rg]) & 0xFFFFFC00u)
                        | (idbase + (uint32_t)col);
            #pragma unroll
            for (int ct = 1; ct < 4; ct++) {
                uint32_t key = (__float_as_uint(acc[ct][rg]) & 0xFFFFFC00u)
                               | (idbase + (uint32_t)(ct * 16 + col));
                if (key < best4[rg]) best4[rg] = key;
            }
        }
        #pragma unroll
        for (int off = 1; off < 16; off <<= 1)
            #pragma unroll
            for (int rg = 0; rg < 4; rg++) {
                uint32_t o = __shfl_xor(best4[rg], off);
                if (o < best4[rg]) best4[rg] = o;
            }
        if (col == 0) {
            #pragma unroll
            for (int rg = 0; rg < 4; rg++)
                pkey[(size_t)(row0 + quad * 4 + rg) * NCG + cg] = best4[rg];
        }
    }
}

// ---------------------------------------------------------------- kernel 3
// Per row: min over 128 group keys (coalesced [M][NCG] reads) -> final code;
// exact fp32 ||x-c||^2; per-block LDS reduce -> partial[bid]; fused k_write
// via release/acquire ticket (R19-proven): last block sums partial[] in
// fixed order and writes out.
__global__ void k_finalize(const uint32_t* __restrict__ pkey,
                           const float4* __restrict__ xs4,
                           const float4* __restrict__ cb4,
                           float* __restrict__ partial,
                           uint32_t* __restrict__ cnt,
                           float* __restrict__ out) {
    __shared__ float sblk[4];
    __shared__ int   last;
    const int w   = threadIdx.x >> 6;
    const int l   = threadIdx.x & 63;
    const int row = blockIdx.x * 4 + w;

    uint32_t k1 = pkey[(size_t)row * NCG + l];        // cg = l
    uint32_t k2 = pkey[(size_t)row * NCG + 64 + l];   // cg = 64+l
    uint32_t k;  int g;
    if (k2 < k1) { k = k2; g = 64 + l; } else { k = k1; g = l; }
    #pragma unroll
    for (int off = 1; off < 64; off <<= 1) {
        uint32_t ok = __shfl_xor(k, off);
        int      og = __shfl_xor(g, off);
        if (ok < k || (ok == k && og < g)) { k = ok; g = og; }
    }
    // key low 10 bits = global code & 1023; g>>4 = which 1024-code group
    const int code = (g >> 4) * 1024 + (int)(k & 1023u);

    float4 x = xs4[(size_t)row * 64 + l];
    float4 c = cb4[(size_t)code * 64 + l];
    float dx = x.x - c.x, dy = x.y - c.y, dz = x.z - c.z, dw = x.w - c.w;
    float s = dx * dx + dy * dy + dz * dz + dw * dw;
    #pragma unroll
    for (int off = 32; off; off >>= 1) s += __shfl_xor(s, off);
    if (l == 0) sblk[w] = s;
    __syncthreads();
    if (threadIdx.x == 0) {
        partial[blockIdx.x] = sblk[0] + sblk[1] + sblk[2] + sblk[3];
        __threadfence();                         // release partial
        uint32_t old = atomicAdd(cnt, 1u);       // device-scope
        last = (old == 4095u) ? 1 : 0;
    }
    __syncthreads();
    if (last) {
        __threadfence();                         // acquire all partials
        float t = 0.0f;
        for (int i = threadIdx.x; i < 4096; i += 256) t += partial[i];
        #pragma unroll
        for (int off = 32; off; off >>= 1) t += __shfl_xor(t, off);
        __syncthreads();                         // sblk reuse
        if (l == 0) sblk[w] = t;
        __syncthreads();
        if (threadIdx.x == 0) {
            float tt = sblk[0] + sblk[1] + sblk[2] + sblk[3];
            float commit = tt * INV_N;
            out[0] = 0.25f * commit;   // loss
            out[1] = commit;           // commit_loss
        }
    }
}

extern "C" void kernel_launch(void* const* d_in, const int* in_sizes, int n_in,
                              void* d_out, int out_size, void* d_ws, size_t ws_size,
                              hipStream_t stream) {
    const float* xs = (const float*)d_in[0];
    // d_in[1] = ilens (int64, all == T) -> slice is a no-op, unused
    const float* cb = (const float*)d_in[2];

    char* ws = (char*)d_ws;
    uint32_t*      cnt     = (uint32_t*)(ws);                       // 4 B
    float*         partial = (float*)(ws + 256);                    // 16 KiB
    float*         chalf   = (float*)(ws + 16640);                  // 32 KiB
    unsigned char* cbt     = (unsigned char*)(ws + 49408);          // 2 MiB
    unsigned char* xq      = (unsigned char*)(ws + 2146560);        // 4 MiB
    uint32_t*      pkey    = (uint32_t*)(ws + 6340864);             // 8 MiB

    k_prep<<<768, 256, 0, stream>>>(cb, cbt, chalf, xs, xq, cnt);
    k_gemm_argmin<<<1024, 256, 0, stream>>>(xq, cbt, chalf, pkey);
    k_finalize<<<4096, 256, 0, stream>>>(pkey, (const float4*)xs,
                                         (const float4*)cb, partial, cnt,
                                         (float*)d_out);
}

// Round 10
// 124.289 us; speedup vs baseline: 2.0496x; 1.7554x over previous
//
#include <hip/hip_runtime.h>
#include <stdint.h>

// Problem constants (B=8, T=2048, D=256, K=8192)
#define M_TOK 16384
#define DIM   256
#define KCB   8192
#define NCG   128                  // code-groups of 64 codes (one per wave)
#define SHIFT 512.0f               // positivity shift for score packing
#define INV_N (1.0f / 4194304.0f)  // 1/(B*T*D)
#define SC1   0x7F7F7F7F           // E8M0 scale bytes = 2^0 (op_sel-proof)

typedef __attribute__((ext_vector_type(4))) float f32x4;
typedef __attribute__((ext_vector_type(8))) int   i32x8;

// pack 4 floats -> 4 fp8 e4m3 bytes (one dword)
static __device__ __forceinline__ int pk4(float4 f) {
    int o = __builtin_amdgcn_cvt_pk_fp8_f32(f.x, f.y, 0, false);
    o     = __builtin_amdgcn_cvt_pk_fp8_f32(f.z, f.w, o, true);
    return o;
}

// ---------------------------------------------------------------- kernel 1
// Prep: cbt[chunk][code][16B] = fp8(-c) k-chunk-major; chalf = 0.5||c||^2 +
// SHIFT; xq[chunk][row][16B] = fp8(x). Blocks 0..255: codebook (32 codes
// each); 256..767: xs (32 rows each). (proven absmax 0.0 R19/R20)
__global__ void k_prep(const float* __restrict__ cb,
                       unsigned char* __restrict__ cbt,
                       float* __restrict__ chalf,
                       const float* __restrict__ xs,
                       unsigned char* __restrict__ xq) {
    const int bid = blockIdx.x;
    const int w    = threadIdx.x >> 6;
    const int l    = threadIdx.x & 63;
    const int idx  = l & 31;           // code or row within block
    const int sub  = l >> 5;
    const int grp8 = w * 2 + sub;      // 0..7, two chunks each

    if (bid < 256) {                   // ---- codebook part
        __shared__ float part[8][32];
        const int c0 = bid * 32;
        const float* row = cb + (size_t)(c0 + idx) * DIM;
        float s = 0.0f;
        #pragma unroll
        for (int j = 0; j < 2; j++) {
            int ch = grp8 * 2 + j;
            const float* p = row + ch * 16;
            float4 a = *(const float4*)(p);
            float4 b = *(const float4*)(p + 4);
            float4 c = *(const float4*)(p + 8);
            float4 d = *(const float4*)(p + 12);
            s += a.x*a.x + a.y*a.y + a.z*a.z + a.w*a.w
               + b.x*b.x + b.y*b.y + b.z*b.z + b.w*b.w
               + c.x*c.x + c.y*c.y + c.z*c.z + c.w*c.w
               + d.x*d.x + d.y*d.y + d.z*d.z + d.w*d.w;
            float4 na = {-a.x, -a.y, -a.z, -a.w};
            float4 nb = {-b.x, -b.y, -b.z, -b.w};
            float4 nc = {-c.x, -c.y, -c.z, -c.w};
            float4 nd = {-d.x, -d.y, -d.z, -d.w};
            uint4 r;
            r.x = (unsigned)pk4(na); r.y = (unsigned)pk4(nb);
            r.z = (unsigned)pk4(nc); r.w = (unsigned)pk4(nd);
            *(uint4*)(cbt + ((size_t)ch * KCB + c0 + idx) * 16) = r;
        }
        part[grp8][idx] = s;
        __syncthreads();
        if (w == 0 && l < 32) {
            float t = 0.0f;
            #pragma unroll
            for (int i = 0; i < 8; i++) t += part[i][l];
            chalf[c0 + l] = 0.5f * t + SHIFT;
        }
    } else {                           // ---- xs part (no norm, no negate)
        const int r0  = (bid - 256) * 32;
        const float* row = xs + (size_t)(r0 + idx) * DIM;
        #pragma unroll
        for (int j = 0; j < 2; j++) {
            int ch = grp8 * 2 + j;
            const float* p = row + ch * 16;
            uint4 r;
            r.x = (unsigned)pk4(*(const float4*)(p));
            r.y = (unsigned)pk4(*(const float4*)(p + 4));
            r.z = (unsigned)pk4(*(const float4*)(p + 8));
            r.w = (unsigned)pk4(*(const float4*)(p + 12));
            *(uint4*)(xq + ((size_t)ch * M_TOK + r0 + idx) * 16) = r;
        }
    }
}

// ---------------------------------------------------------------- kernel 2
// R20 (unchanged in R21): B-resident free-running GEMM+argmin.
// launch_bounds(256,2) -> VGPR cap 128 (session law: cap ~= 512/(2N); the
// (256,4) variants capped at 64 and spilled the 64-reg B panel). Straight-
// line step: {4x global_load_dwordx4 -> 8 MFMA -> fold -> 4x shfl -> store};
// no LDS/barriers, waves free-run; compiler hoists next-step loads.
__global__ __launch_bounds__(256, 2) void k_gemm_argmin(
    const unsigned char* __restrict__ xq,      // [16][M_TOK][16] fp8 of x
    const unsigned char* __restrict__ cbt,     // [16][KCB][16] fp8 of -c
    const float* __restrict__ chalf,           // [KCB] = 0.5||c||^2+SHIFT
    uint32_t* __restrict__ pkey)               // [M_TOK][NCG]
{
    const int tid  = threadIdx.x;
    const int w    = tid >> 6;
    const int l    = tid & 63;
    const int col  = l & 15;
    const int quad = l >> 4;
    const int bid  = blockIdx.x;
    // XCD-aware: bid%8 = XCD (heuristic) -> ms in [4x,4x+4): 4 slices/XCD
    const int ms   = (bid & 7) * 4 + ((bid >> 3) & 3);   // 0..31
    const int cg   = (bid >> 5) * 4 + w;                  // 0..127
    const int row0base = ms * 512;
    const int chA = quad * 2, chB = 8 + quad * 2;
    const uint32_t idbase = (uint32_t)((cg & 15) << 6);   // id10 base

    // ---- resident B panel: codes cg*64 + ct*16 + col, 64 VGPRs
    i32x8 bfr[4][2];
    #pragma unroll
    for (int ct = 0; ct < 4; ct++) {
        const int code = cg * 64 + ct * 16 + col;
        #pragma unroll
        for (int ks = 0; ks < 2; ks++) {
            const int ch = ks * 8 + quad * 2;
            union { uint4 q[2]; i32x8 v; } bb;
            bb.q[0] = *(const uint4*)(cbt + ((size_t)ch * KCB + code) * 16);
            bb.q[1] = *(const uint4*)(cbt + ((size_t)(ch + 1) * KCB + code) * 16);
            bfr[ct][ks] = bb.v;
        }
    }
    float cs[4];
    #pragma unroll
    for (int ct = 0; ct < 4; ct++)
        cs[ct] = chalf[cg * 64 + ct * 16 + col];

    #pragma unroll 1
    for (int s = 0; s < 32; ++s) {
        const int row0 = row0base + s * 16;
        const size_t arow = (size_t)(row0 + col) * 16;
        // all 4 A-loads up front (max memory-level parallelism; 16 VGPRs)
        uint4 A0a = *(const uint4*)(xq + (size_t)chA * (M_TOK * 16) + arow);
        uint4 A0b = *(const uint4*)(xq + (size_t)(chA + 1) * (M_TOK * 16) + arow);
        uint4 A1a = *(const uint4*)(xq + (size_t)chB * (M_TOK * 16) + arow);
        uint4 A1b = *(const uint4*)(xq + (size_t)(chB + 1) * (M_TOK * 16) + arow);
        union { uint4 q[2]; i32x8 v; } ua0; ua0.q[0] = A0a; ua0.q[1] = A0b;
        union { uint4 q[2]; i32x8 v; } ua1; ua1.q[0] = A1a; ua1.q[1] = A1b;

        // scores: C-init with cs splat, ks0 then ks1 (R1-identical chain)
        f32x4 acc[4];
        #pragma unroll
        for (int ct = 0; ct < 4; ct++) {
            f32x4 c4 = {cs[ct], cs[ct], cs[ct], cs[ct]};
            acc[ct] = __builtin_amdgcn_mfma_scale_f32_16x16x128_f8f6f4(
                ua0.v, bfr[ct][0], c4, 0, 0, 0, SC1, 0, SC1);
        }
        #pragma unroll
        for (int ct = 0; ct < 4; ct++)
            acc[ct] = __builtin_amdgcn_mfma_scale_f32_16x16x128_f8f6f4(
                ua1.v, bfr[ct][1], acc[ct], 0, 0, 0, SC1, 0, SC1);

        // fold to packed keys (R1-verified scheme: score&~1023 | id10)
        uint32_t best4[4];
        #pragma unroll
        for (int rg = 0; rg < 4; rg++) {
            best4[rg] = (__float_as_uint(acc[0][rg]) & 0xFFFFFC00u)
                        | (idbase + (uint32_t)col);
            #pragma unroll
            for (int ct = 1; ct < 4; ct++) {
                uint32_t key = (__float_as_uint(acc[ct][rg]) & 0xFFFFFC00u)
                               | (idbase + (uint32_t)(ct * 16 + col));
                if (key < best4[rg]) best4[rg] = key;
            }
        }
        #pragma unroll
        for (int off = 1; off < 16; off <<= 1)
            #pragma unroll
            for (int rg = 0; rg < 4; rg++) {
                uint32_t o = __shfl_xor(best4[rg], off);
                if (o < best4[rg]) best4[rg] = o;
            }
        if (col == 0) {
            #pragma unroll
            for (int rg = 0; rg < 4; rg++)
                pkey[(size_t)(row0 + quad * 4 + rg) * NCG + cg] = best4[rg];
        }
    }
}

// ---------------------------------------------------------------- kernel 3
// R21: fence/ticket REMOVED (R20 post-mortem: per-block device-scope
// __threadfence on non-coherent XCD L2s = L2 writeback per block -> 105us
// of wait with 2% BW. The fused k_write saved ~5us launch, cost ~80us).
// Back to R1-proven: write partial[bid], stream order handles visibility.
__global__ void k_finalize(const uint32_t* __restrict__ pkey,
                           const float4* __restrict__ xs4,
                           const float4* __restrict__ cb4,
                           float* __restrict__ partial) {
    __shared__ float sblk[4];
    const int w   = threadIdx.x >> 6;
    const int l   = threadIdx.x & 63;
    const int row = blockIdx.x * 4 + w;

    uint32_t k1 = pkey[(size_t)row * NCG + l];        // cg = l
    uint32_t k2 = pkey[(size_t)row * NCG + 64 + l];   // cg = 64+l
    uint32_t k;  int g;
    if (k2 < k1) { k = k2; g = 64 + l; } else { k = k1; g = l; }
    #pragma unroll
    for (int off = 1; off < 64; off <<= 1) {
        uint32_t ok = __shfl_xor(k, off);
        int      og = __shfl_xor(g, off);
        if (ok < k || (ok == k && og < g)) { k = ok; g = og; }
    }
    // key low 10 bits = global code & 1023; g>>4 = which 1024-code group
    const int code = (g >> 4) * 1024 + (int)(k & 1023u);

    float4 x = xs4[(size_t)row * 64 + l];
    float4 c = cb4[(size_t)code * 64 + l];
    float dx = x.x - c.x, dy = x.y - c.y, dz = x.z - c.z, dw = x.w - c.w;
    float s = dx * dx + dy * dy + dz * dz + dw * dw;
    #pragma unroll
    for (int off = 32; off; off >>= 1) s += __shfl_xor(s, off);
    if (l == 0) sblk[w] = s;
    __syncthreads();
    if (threadIdx.x == 0)
        partial[blockIdx.x] = sblk[0] + sblk[1] + sblk[2] + sblk[3];
}

// ---------------------------------------------------------------- kernel 4
__global__ void k_write(const float* __restrict__ partial,
                        float* __restrict__ out) {
    __shared__ float swv[16];
    int tid = threadIdx.x;                    // 1024 threads = 16 waves
    float s = partial[tid] + partial[tid + 1024] +
              partial[tid + 2048] + partial[tid + 3072];
    #pragma unroll
    for (int off = 32; off; off >>= 1) s += __shfl_xor(s, off);
    if ((tid & 63) == 0) swv[tid >> 6] = s;
    __syncthreads();
    if (tid == 0) {
        float t = 0.0f;
        #pragma unroll
        for (int i = 0; i < 16; i++) t += swv[i];
        float commit = t * INV_N;
        out[0] = 0.25f * commit;   // loss
        out[1] = commit;           // commit_loss
    }
}

extern "C" void kernel_launch(void* const* d_in, const int* in_sizes, int n_in,
                              void* d_out, int out_size, void* d_ws, size_t ws_size,
                              hipStream_t stream) {
    const float* xs = (const float*)d_in[0];
    // d_in[1] = ilens (int64, all == T) -> slice is a no-op, unused
    const float* cb = (const float*)d_in[2];

    char* ws = (char*)d_ws;
    float*         partial = (float*)(ws + 256);                    // 16 KiB
    float*         chalf   = (float*)(ws + 16640);                  // 32 KiB
    unsigned char* cbt     = (unsigned char*)(ws + 49408);          // 2 MiB
    unsigned char* xq      = (unsigned char*)(ws + 2146560);        // 4 MiB
    uint32_t*      pkey    = (uint32_t*)(ws + 6340864);             // 8 MiB

    k_prep<<<768, 256, 0, stream>>>(cb, cbt, chalf, xs, xq);
    k_gemm_argmin<<<1024, 256, 0, stream>>>(xq, cbt, chalf, pkey);
    k_finalize<<<4096, 256, 0, stream>>>(pkey, (const float4*)xs,
                                         (const float4*)cb, partial);
    k_write<<<1, 1024, 0, stream>>>(partial, (float*)d_out);
}

// Round 11
// 120.449 us; speedup vs baseline: 2.1150x; 1.0319x over previous
//
#include <hip/hip_runtime.h>
#include <stdint.h>

// Problem constants (B=8, T=2048, D=256, K=8192)
#define M_TOK 16384
#define DIM   256
#define KCB   8192
#define NCG   128                  // code-groups of 64 codes (one per wave)
#define SHIFT 512.0f               // positivity shift for score packing
#define INV_N (1.0f / 4194304.0f)  // 1/(B*T*D)
#define SC1   0x7F7F7F7F           // E8M0 scale bytes = 2^0 (op_sel-proof)

typedef __attribute__((ext_vector_type(4))) float f32x4;
typedef __attribute__((ext_vector_type(8))) int   i32x8;

// pack 4 floats -> 4 fp8 e4m3 bytes (one dword)
static __device__ __forceinline__ int pk4(float4 f) {
    int o = __builtin_amdgcn_cvt_pk_fp8_f32(f.x, f.y, 0, false);
    o     = __builtin_amdgcn_cvt_pk_fp8_f32(f.z, f.w, o, true);
    return o;
}

// ---------------------------------------------------------------- kernel 1
// Prep: cbt[chunk][code][16B] = fp8(-c) k-chunk-major; chalf = 0.5||c||^2 +
// SHIFT; xq[chunk][row][16B] = fp8(x). Blocks 0..255: codebook (32 codes
// each); 256..767: xs (32 rows each). (proven absmax 0.0 R19-R21)
__global__ void k_prep(const float* __restrict__ cb,
                       unsigned char* __restrict__ cbt,
                       float* __restrict__ chalf,
                       const float* __restrict__ xs,
                       unsigned char* __restrict__ xq) {
    const int bid = blockIdx.x;
    const int w    = threadIdx.x >> 6;
    const int l    = threadIdx.x & 63;
    const int idx  = l & 31;           // code or row within block
    const int sub  = l >> 5;
    const int grp8 = w * 2 + sub;      // 0..7, two chunks each

    if (bid < 256) {                   // ---- codebook part
        __shared__ float part[8][32];
        const int c0 = bid * 32;
        const float* row = cb + (size_t)(c0 + idx) * DIM;
        float s = 0.0f;
        #pragma unroll
        for (int j = 0; j < 2; j++) {
            int ch = grp8 * 2 + j;
            const float* p = row + ch * 16;
            float4 a = *(const float4*)(p);
            float4 b = *(const float4*)(p + 4);
            float4 c = *(const float4*)(p + 8);
            float4 d = *(const float4*)(p + 12);
            s += a.x*a.x + a.y*a.y + a.z*a.z + a.w*a.w
               + b.x*b.x + b.y*b.y + b.z*b.z + b.w*b.w
               + c.x*c.x + c.y*c.y + c.z*c.z + c.w*c.w
               + d.x*d.x + d.y*d.y + d.z*d.z + d.w*d.w;
            float4 na = {-a.x, -a.y, -a.z, -a.w};
            float4 nb = {-b.x, -b.y, -b.z, -b.w};
            float4 nc = {-c.x, -c.y, -c.z, -c.w};
            float4 nd = {-d.x, -d.y, -d.z, -d.w};
            uint4 r;
            r.x = (unsigned)pk4(na); r.y = (unsigned)pk4(nb);
            r.z = (unsigned)pk4(nc); r.w = (unsigned)pk4(nd);
            *(uint4*)(cbt + ((size_t)ch * KCB + c0 + idx) * 16) = r;
        }
        part[grp8][idx] = s;
        __syncthreads();
        if (w == 0 && l < 32) {
            float t = 0.0f;
            #pragma unroll
            for (int i = 0; i < 8; i++) t += part[i][l];
            chalf[c0 + l] = 0.5f * t + SHIFT;
        }
    } else {                           // ---- xs part (no norm, no negate)
        const int r0  = (bid - 256) * 32;
        const float* row = xs + (size_t)(r0 + idx) * DIM;
        #pragma unroll
        for (int j = 0; j < 2; j++) {
            int ch = grp8 * 2 + j;
            const float* p = row + ch * 16;
            uint4 r;
            r.x = (unsigned)pk4(*(const float4*)(p));
            r.y = (unsigned)pk4(*(const float4*)(p + 4));
            r.z = (unsigned)pk4(*(const float4*)(p + 8));
            r.w = (unsigned)pk4(*(const float4*)(p + 12));
            *(uint4*)(xq + ((size_t)ch * M_TOK + r0 + idx) * 16) = r;
        }
    }
}

// ---------------------------------------------------------------- kernel 2
// R22: B-resident free-running GEMM+argmin, ARCH-REGISTER DIET for 4
// blocks/CU. R21 evidence: VGPR_Count=64(arch) + ~80 acc-side (B panel 64 +
// acc 16) = ~144/wave -> 12 waves/CU (occupancy 37.5%) -> 1024-block grid
// runs 768+256 = 27% tail; VALUBusy(36.5%) > MfmaUtil(28%). Diet: (a)
// saddr-form A loads (wave-uniform xq+row0*16 base in SGPR, 4 loop-invariant
// 32b lane offsets; zero per-step vector addr math); (b) pkey stores via
// uniform base + 1 VGPR offset + imm-folded 512B steps; (c) precomputed
// idc[ct] key constants. Arch-side live ~43 < 48 target; (256,4) caps total
// at 128 -> 16 waves/CU, zero tail. Spill tripwire: WRITE_SIZE >> 8.2MB.
// T5 setprio around MFMA cluster (free-running waves = role diversity).
__global__ __launch_bounds__(256, 4) void k_gemm_argmin(
    const unsigned char* __restrict__ xq,      // [16][M_TOK][16] fp8 of x
    const unsigned char* __restrict__ cbt,     // [16][KCB][16] fp8 of -c
    const float* __restrict__ chalf,           // [KCB] = 0.5||c||^2+SHIFT
    uint32_t* __restrict__ pkey)               // [M_TOK][NCG]
{
    const int tid  = threadIdx.x;
    const int w    = tid >> 6;
    const int l    = tid & 63;
    const int col  = l & 15;
    const int quad = l >> 4;
    const int bid  = blockIdx.x;
    // XCD-aware: bid%8 = XCD (heuristic) -> ms in [4x,4x+4): 4 slices/XCD
    const int ms   = (bid & 7) * 4 + ((bid >> 3) & 3);   // 0..31
    const int cg   = (bid >> 5) * 4 + w;                  // 0..127
    const int row0base = ms * 512;
    const int chA = quad * 2, chB = 8 + quad * 2;
    const uint32_t idbase = (uint32_t)((cg & 15) << 6);   // id10 base

    // ---- resident B panel: codes cg*64 + ct*16 + col (64 regs, acc-side)
    i32x8 bfr[4][2];
    #pragma unroll
    for (int ct = 0; ct < 4; ct++) {
        const int code = cg * 64 + ct * 16 + col;
        #pragma unroll
        for (int ks = 0; ks < 2; ks++) {
            const int ch = ks * 8 + quad * 2;
            union { uint4 q[2]; i32x8 v; } bb;
            bb.q[0] = *(const uint4*)(cbt + ((size_t)ch * KCB + code) * 16);
            bb.q[1] = *(const uint4*)(cbt + ((size_t)(ch + 1) * KCB + code) * 16);
            bfr[ct][ks] = bb.v;
        }
    }
    float cs[4];
    #pragma unroll
    for (int ct = 0; ct < 4; ct++)
        cs[ct] = chalf[cg * 64 + ct * 16 + col];
    // precomputed key-id constants (kills per-step id arithmetic)
    uint32_t idc[4];
    #pragma unroll
    for (int ct = 0; ct < 4; ct++)
        idc[ct] = idbase + (uint32_t)(ct * 16 + col);

    // loop-invariant lane byte-offsets for the 4 A-plane loads (saddr form)
    const uint32_t voffA0 = ((uint32_t)chA * M_TOK + (uint32_t)col) * 16u;
    const uint32_t voffA1 = ((uint32_t)(chA + 1) * M_TOK + (uint32_t)col) * 16u;
    const uint32_t voffB0 = ((uint32_t)chB * M_TOK + (uint32_t)col) * 16u;
    const uint32_t voffB1 = ((uint32_t)(chB + 1) * M_TOK + (uint32_t)col) * 16u;
    // store-side lane offset (dwords); rg steps fold to imm offsets (+512B)
    const uint32_t soff = (uint32_t)(quad * 4) * NCG + (uint32_t)cg;

    #pragma unroll 1
    for (int s = 0; s < 32; ++s) {
        const int row0 = row0base + s * 16;                 // wave-uniform
        const unsigned char* up = xq + (size_t)row0 * 16;   // SGPR base
        uint4 A0a = *(const uint4*)(up + voffA0);
        uint4 A0b = *(const uint4*)(up + voffA1);
        uint4 A1a = *(const uint4*)(up + voffB0);
        uint4 A1b = *(const uint4*)(up + voffB1);
        union { uint4 q[2]; i32x8 v; } ua0; ua0.q[0] = A0a; ua0.q[1] = A0b;
        union { uint4 q[2]; i32x8 v; } ua1; ua1.q[0] = A1a; ua1.q[1] = A1b;

        // scores: C-init with cs splat, ks0 then ks1 (R1-identical chain)
        f32x4 acc[4];
        __builtin_amdgcn_s_setprio(1);
        #pragma unroll
        for (int ct = 0; ct < 4; ct++) {
            f32x4 c4 = {cs[ct], cs[ct], cs[ct], cs[ct]};
            acc[ct] = __builtin_amdgcn_mfma_scale_f32_16x16x128_f8f6f4(
                ua0.v, bfr[ct][0], c4, 0, 0, 0, SC1, 0, SC1);
        }
        #pragma unroll
        for (int ct = 0; ct < 4; ct++)
            acc[ct] = __builtin_amdgcn_mfma_scale_f32_16x16x128_f8f6f4(
                ua1.v, bfr[ct][1], acc[ct], 0, 0, 0, SC1, 0, SC1);
        __builtin_amdgcn_s_setprio(0);

        // fold to packed keys (R1-verified scheme: score&~1023 | id10)
        uint32_t best4[4];
        #pragma unroll
        for (int rg = 0; rg < 4; rg++) {
            best4[rg] = (__float_as_uint(acc[0][rg]) & 0xFFFFFC00u) | idc[0];
            #pragma unroll
            for (int ct = 1; ct < 4; ct++) {
                uint32_t key =
                    (__float_as_uint(acc[ct][rg]) & 0xFFFFFC00u) | idc[ct];
                if (key < best4[rg]) best4[rg] = key;
            }
        }
        #pragma unroll
        for (int off = 1; off < 16; off <<= 1)
            #pragma unroll
            for (int rg = 0; rg < 4; rg++) {
                uint32_t o = __shfl_xor(best4[rg], off);
                if (o < best4[rg]) best4[rg] = o;
            }
        if (col == 0) {
            uint32_t* pp = pkey + (size_t)row0 * NCG;       // SGPR base
            #pragma unroll
            for (int rg = 0; rg < 4; rg++)
                pp[soff + (uint32_t)rg * NCG] = best4[rg];
        }
    }
}

// ---------------------------------------------------------------- kernel 3
// Per row: min over 128 group keys (coalesced [M][NCG] reads) -> final code;
// exact fp32 ||x-c||^2; per-block LDS reduce -> partial[bid]. No fences
// (R20 lesson: per-block device fence on non-coherent XCD L2s cost ~80us).
__global__ void k_finalize(const uint32_t* __restrict__ pkey,
                           const float4* __restrict__ xs4,
                           const float4* __restrict__ cb4,
                           float* __restrict__ partial) {
    __shared__ float sblk[4];
    const int w   = threadIdx.x >> 6;
    const int l   = threadIdx.x & 63;
    const int row = blockIdx.x * 4 + w;

    uint32_t k1 = pkey[(size_t)row * NCG + l];        // cg = l
    uint32_t k2 = pkey[(size_t)row * NCG + 64 + l];   // cg = 64+l
    uint32_t k;  int g;
    if (k2 < k1) { k = k2; g = 64 + l; } else { k = k1; g = l; }
    #pragma unroll
    for (int off = 1; off < 64; off <<= 1) {
        uint32_t ok = __shfl_xor(k, off);
        int      og = __shfl_xor(g, off);
        if (ok < k || (ok == k && og < g)) { k = ok; g = og; }
    }
    // key low 10 bits = global code & 1023; g>>4 = which 1024-code group
    const int code = (g >> 4) * 1024 + (int)(k & 1023u);

    float4 x = xs4[(size_t)row * 64 + l];
    float4 c = cb4[(size_t)code * 64 + l];
    float dx = x.x - c.x, dy = x.y - c.y, dz = x.z - c.z, dw = x.w - c.w;
    float s = dx * dx + dy * dy + dz * dz + dw * dw;
    #pragma unroll
    for (int off = 32; off; off >>= 1) s += __shfl_xor(s, off);
    if (l == 0) sblk[w] = s;
    __syncthreads();
    if (threadIdx.x == 0)
        partial[blockIdx.x] = sblk[0] + sblk[1] + sblk[2] + sblk[3];
}

// ---------------------------------------------------------------- kernel 4
__global__ void k_write(const float* __restrict__ partial,
                        float* __restrict__ out) {
    __shared__ float swv[16];
    int tid = threadIdx.x;                    // 1024 threads = 16 waves
    float s = partial[tid] + partial[tid + 1024] +
              partial[tid + 2048] + partial[tid + 3072];
    #pragma unroll
    for (int off = 32; off; off >>= 1) s += __shfl_xor(s, off);
    if ((tid & 63) == 0) swv[tid >> 6] = s;
    __syncthreads();
    if (tid == 0) {
        float t = 0.0f;
        #pragma unroll
        for (int i = 0; i < 16; i++) t += swv[i];
        float commit = t * INV_N;
        out[0] = 0.25f * commit;   // loss
        out[1] = commit;           // commit_loss
    }
}

extern "C" void kernel_launch(void* const* d_in, const int* in_sizes, int n_in,
                              void* d_out, int out_size, void* d_ws, size_t ws_size,
                              hipStream_t stream) {
    const float* xs = (const float*)d_in[0];
    // d_in[1] = ilens (int64, all == T) -> slice is a no-op, unused
    const float* cb = (const float*)d_in[2];

    char* ws = (char*)d_ws;
    float*         partial = (float*)(ws + 256);                    // 16 KiB
    float*         chalf   = (float*)(ws + 16640);                  // 32 KiB
    unsigned char* cbt     = (unsigned char*)(ws + 49408);          // 2 MiB
    unsigned char* xq      = (unsigned char*)(ws + 2146560);        // 4 MiB
    uint32_t*      pkey    = (uint32_t*)(ws + 6340864);             // 8 MiB

    k_prep<<<768, 256, 0, stream>>>(cb, cbt, chalf, xs, xq);
    k_gemm_argmin<<<1024, 256, 0, stream>>>(xq, cbt, chalf, pkey);
    k_finalize<<<4096, 256, 0, stream>>>(pkey, (const float4*)xs,
                                         (const float4*)cb, partial);
    k_write<<<1, 1024, 0, stream>>>(partial, (float*)d_out);
}